// Round 5
// baseline (1920.203 us; speedup 1.0000x reference)
//
#include <hip/hip_runtime.h>

#define TT 365
#define BB 512
#define DD 16
#define HH 256
#define SS 32

typedef __attribute__((ext_vector_type(8))) short short8;
typedef __attribute__((ext_vector_type(4))) float f32x4;
typedef __attribute__((ext_vector_type(4))) unsigned u32x4;
typedef unsigned long long u64;

// Ring poison: tag bits (14,30) set in both dwords = tag-code 3; first poll of
// any address wants code 0 => mismatch; codes 1,2 are written before 3 recurs.
#define SENT 0x7FC07FC07FC07FC0ULL
// 2-bit generation tag per dword: bit14 (low bf16) + bit30 (high bf16).
// |h|<=1 => biased exp <= 127 => both bits are 0 in any published bf16.
#define TMASK64 0x4000400040004000ULL

__device__ __host__ inline short f2bf(float f){
  union { float f; unsigned u; } v; v.f = f;
  unsigned r = v.u + 0x7FFFu + ((v.u >> 16) & 1u);
  return (short)(r >> 16);
}
__device__ inline float sigm(float x){ return 1.0f/(1.0f+__expf(-x)); }
__device__ inline float tanhx(float x){ return 2.0f/(1.0f+__expf(-2.0f*x)) - 1.0f; }

// RNE f32x2 -> packed bf16x2 (same rounding as f2bf; h is never NaN)
__device__ inline unsigned cvtpk(float a, float b){
  unsigned r;
  asm("v_cvt_pk_bf16_f32 %0, %1, %2" : "=v"(r) : "v"(a), "v"(b));
  return r;
}

// A-fragment address (shorts) in an 8KB K=256 region for mfma_16x16x32 A-layout.
__device__ inline int fragAddr(int k, int m){
  return ((k>>5)*512) + ((((k&31)>>3)*16 + m)*8) + (k&7);
}

// Coherence-point store (HW-verified visible to sc0+sc1 polls in R2/R3).
__device__ inline void pub_store(u64* p, u64 v){
  asm volatile("global_store_dwordx2 %0, %1, off sc0 sc1"
               :: "v"(p), "v"(v) : "memory");
}

// ---------------- prep kernels ----------------
__global__ void prep_weights(const float* __restrict__ Wih0, const float* __restrict__ Whh0,
                             const float* __restrict__ Wih1, const float* __restrict__ Whh1,
                             short* __restrict__ Wb0, short* __restrict__ Wb1)
{
  int idx = blockIdx.x*blockDim.x + threadIdx.x;
  const int n0 = 16*36*512;
  const int n1 = 16*64*512;
  if (idx < n0){
    int frag = idx >> 9, pos = idx & 511;
    int lane = pos >> 3, jj = pos & 7;
    int slot = frag / 36, rem = frag % 36;
    int ks = rem >> 2, nt = rem & 3;
    int n = nt*256 + slot*16 + (lane & 15);
    float v = 0.0f;
    if (ks == 0){
      int k32 = (lane>>4)*8 + jj;
      if (k32 < 16) v = Wih0[n*16 + k32];
    } else {
      int k = (ks-1)*32 + (lane>>4)*8 + jj;
      v = Whh0[n*256 + k];
    }
    Wb0[idx] = f2bf(v);
  } else if (idx < n0 + n1){
    int e = idx - n0;
    int frag = e >> 9, pos = e & 511;
    int lane = pos >> 3, jj = pos & 7;
    int slot = frag >> 6, rem = frag & 63;
    int ks = rem >> 2, nt = rem & 3;
    int n = nt*256 + slot*16 + (lane & 15);
    int k = ks*32 + (lane>>4)*8 + jj;
    float v = (k < 256) ? Wih1[n*256 + k] : Whh1[n*256 + (k-256)];
    Wb1[e] = f2bf(v);
  }
}

__global__ void prep_h0(const float* __restrict__ xs, const float* __restrict__ Ws,
                        const float* __restrict__ bs, float* __restrict__ h0init)
{
  int i = blockIdx.x*blockDim.x + threadIdx.x;
  int b = i >> 8, jj = i & 255;
  float s = bs[jj];
  const float* xr = xs + b*SS;
  const float* wr = Ws + jj*SS;
#pragma unroll
  for (int q=0;q<SS;++q) s += xr[q]*wr[q];
  h0init[i] = s;
}

__global__ void prep_bias(const float* __restrict__ a0, const float* __restrict__ a1,
                          const float* __restrict__ a2, const float* __restrict__ a3,
                          float* __restrict__ b0o, float* __restrict__ b1o)
{
  int i = threadIdx.x + blockIdx.x*blockDim.x;
  if (i < 1024) b0o[i] = a0[i] + a1[i];
  else if (i < 2048) b1o[i-1024] = a2[i-1024] + a3[i-1024];
}

// zero out (atomicAdd target) + pre-poison ring (tag code 3 => no false match)
__global__ void prep_zero(float* __restrict__ out, u64* __restrict__ ring)
{
  int i = blockIdx.x*blockDim.x + threadIdx.x;
  if (i < BB*TT) out[i] = 0.0f;
  if (i < 131072) ring[i] = SENT;   // 2 slots x 32 g x 2048 u64 = 1MB
}

// ---------------- persistent fused LSTM ----------------
// 128 blocks x 256 threads; g = bid&31 (16 batch rows), c = bid>>5 (64 hidden cols).
// Weights register/AGPR-resident. Lag pipeline: superstep s runs L0@t=s, L1@t=s-1.
//
// Exchange: generation-tagged packets {h0(s), h1(s-1)}, slot s&1, 2-BIT tag
// T=(s>>1)&3 in (bit14,bit30) of every dword. Same slot+tag recurs only at
// Delta-s=8; mutual consumption bounds skew<=1 => no ABA. Polls are read-only
// sc0+sc1 loads (HW-verified visibility in R2/R3); publishes are sc0+sc1
// stores. No atomics, no fences, one barrier per step.
//
// Early-issue schedule (critical path = h0 recurrence only):
//   L0 MFMAs -> epi -> publish h0(s) -> own h0 frags -> ISSUE h0 polls
//   L1 MFMAs -> epi -> publish h1(s-1) -> ISSUE h1 polls -> own h1 frags -> reduce
//   AX stage -> vmcnt(0) + sched_barrier (rule-#18) -> check/retry -> partner
//   frags -> BAR -> out atomicAdd.
// Poll RTT hides under the entire L1 phase.
// Ring word layout (u64): (slot*32+g)*2048 + (k*4+quad)*2 + {0:h0, 1:h1}.
__global__ __launch_bounds__(256, 1) void lstm_fused(
    const short* __restrict__ Wb0, const short* __restrict__ Wb1,
    const float* __restrict__ h0i, const float* __restrict__ b0c,
    const float* __restrict__ b1c, const float* __restrict__ x,
    const float* __restrict__ Wo, const float* __restrict__ bo,
    u64* __restrict__ ring, float* __restrict__ out)
{
  __shared__ alignas(16) short AX[2][512];
  __shared__ alignas(16) short AH0[2][4096];
  __shared__ alignas(16) short AH1[2][4096];
  __shared__ float outacc[2][16][4];

  const int tid  = threadIdx.x;
  const int w    = tid >> 6;
  const int lane = tid & 63;
  const int col16= lane & 15;
  const int quad = lane >> 4;
  const int c    = blockIdx.x >> 5;
  const int g    = blockIdx.x & 31;
  const int rowbase = g * 16;
  const int slot = c*4 + w;
  const int colg = slot*16 + col16;

  // ---- register-resident weight fragments ----
  short8 F0[36], F1[64];
  {
    const short8* p0 = (const short8*)Wb0 + slot*36*64 + lane;
#pragma unroll
    for (int f=0; f<36; ++f) F0[f] = p0[f*64];
    const short8* p1 = (const short8*)Wb1 + slot*64*64 + lane;
#pragma unroll
    for (int f=0; f<64; ++f) F1[f] = p1[f*64];
  }
  float bia0[4], bia1[4];
#pragma unroll
  for (int nt=0; nt<4; ++nt){
    bia0[nt] = b0c[nt*256 + slot*16 + col16];
    bia1[nt] = b1c[nt*256 + slot*16 + col16];
  }
  const float wo = Wo[colg];
  const float bos = bo[0];

  // ---- init (both buffers) ----
  float c0[4], c1[4];
#pragma unroll
  for (int r=0; r<4; ++r){
    c0[r] = h0i[(rowbase + quad*4 + r)*HH + colg];
    c1[r] = c0[r];
  }
  for (int i = tid; i < 4096; i += 256){
    int m = i >> 8, k = i & 255;
    short v = f2bf(h0i[(rowbase+m)*HH + k]);
    int a = fragAddr(k,m);
    AH0[0][a] = v; AH0[1][a] = v;
    AH1[0][a] = v; AH1[1][a] = v;
  }
  {
    int m = tid >> 4, d = tid & 15;
    short v = f2bf(x[(rowbase+m)*TT*DD + d]);
    AX[0][fragAddr(d, m)] = v;      AX[1][fragAddr(d, m)] = v;
    AX[0][fragAddr(16 + d, m)] = 0; AX[1][fragAddr(16 + d, m)] = 0;
  }
  __syncthreads();

  const f32x4 zero = {0.0f,0.0f,0.0f,0.0f};
  const int qd = tid & 3;
  const int cl = (tid >> 2) & 63;
  const int ka = (((c + 1) & 3) << 6) + cl;
  const int kb = (((c + 2) & 3) << 6) + cl;
  const int kc = (((c + 3) & 3) << 6) + cl;

#define CHKW(tv,dst,fl) do{ u64 _t=(tv); \
    if(!(fl) && ((_t & TMASK64)==tg64)){ (dst)=_t & ~TMASK64; (fl)=true; } }while(0)

  for (int s=0; s<=TT; ++s){
    const bool doL0 = (s < TT);
    const bool doL1 = (s >= 1);
    const int  p = s & 1;
    const unsigned T = (s>>1)&3;
    const unsigned t32 = ((T&1)?0x4000u:0u) | ((T&2)?0x40000000u:0u);
    const u64 tg64 = ((u64)t32 << 32) | t32;
    short* ax   = AX[p];   short* ah0   = AH0[p];   short* ah1   = AH1[p];
    short* ax_n = AX[p^1]; short* ah0_n = AH0[p^1]; short* ah1_n = AH1[p^1];
    u64* rbase = ring + (p*32+g)*2048;
    u64* Pa = rbase + (ka*4+qd)*2;
    u64* Pb = rbase + (kb*4+qd)*2;
    u64* Pc = rbase + (kc*4+qd)*2;

    // prefetch x_{s+1} (hidden under MFMAs)
    float xf = 0.0f;
    if (s+1 < TT){
      int m = tid >> 4, d = tid & 15;
      xf = x[(rowbase+m)*TT*DD + (s+1)*DD + d];
    }

    u64 pv0 = 0, pv1 = 0;
    u64 e0a=0, e0b=0, e0c=0, e1a=0, e1b=0, e1c=0;

    // ---- L0: MFMAs -> epi -> publish h0(s) -> own frags -> EARLY h0 polls ----
    if (doL0){
      f32x4 acc0[4];
#pragma unroll
      for (int nt=0; nt<4; ++nt) acc0[nt] = zero;
      {
        short8 a = *(const short8*)(ax + lane*8);
#pragma unroll
        for (int nt=0; nt<4; ++nt)
          acc0[nt] = __builtin_amdgcn_mfma_f32_16x16x32_bf16(a, F0[nt], acc0[nt], 0,0,0);
      }
#pragma unroll
      for (int ks=0; ks<8; ++ks){
        short8 a = *(const short8*)(ah0 + ks*512 + lane*8);
#pragma unroll
        for (int nt=0; nt<4; ++nt)
          acc0[nt] = __builtin_amdgcn_mfma_f32_16x16x32_bf16(a, F0[(ks+1)*4+nt], acc0[nt], 0,0,0);
      }
      float h0v[4];
#pragma unroll
      for (int r=0; r<4; ++r){
        float iv = sigm (acc0[0][r] + bia0[0]);
        float fv = sigm (acc0[1][r] + bia0[1]);
        float gv = tanhx(acc0[2][r] + bia0[2]);
        float ov = sigm (acc0[3][r] + bia0[3]);
        float cc = fv*c0[r] + iv*gv;
        c0[r] = cc;
        h0v[r] = ov * tanhx(cc);
      }
      unsigned lo = cvtpk(h0v[0], h0v[1]);
      unsigned hi = cvtpk(h0v[2], h0v[3]);
      pv0 = ((u64)hi << 32) | lo;
      pub_store(rbase + (colg*4+quad)*2, pv0 | tg64);

      // own h0 frags into next buffer (no race: others read buf p)
#pragma unroll
      for (int r=0; r<4; ++r)
        ah0_n[fragAddr(colg, quad*4 + r)] = (short)(pv0 >> (16*r));

      // EARLY poll issue A: partner h0 words (RTT hides under L1 phase)
      asm volatile(
        "global_load_dwordx2 %0, %3, off sc0 sc1\n\t"
        "global_load_dwordx2 %1, %4, off sc0 sc1\n\t"
        "global_load_dwordx2 %2, %5, off sc0 sc1"
        : "=&v"(e0a),"=&v"(e0b),"=&v"(e0c)
        : "v"(Pa),"v"(Pb),"v"(Pc) : "memory");
    }

    // ---- L1: MFMAs -> epi -> publish h1(s-1) -> EARLY h1 polls -> reduce ----
    if (doL1){
      f32x4 acc1[4];
#pragma unroll
      for (int nt=0; nt<4; ++nt) acc1[nt] = zero;
#pragma unroll
      for (int ks=0; ks<8; ++ks){
        short8 a = *(const short8*)(ah0 + ks*512 + lane*8);
#pragma unroll
        for (int nt=0; nt<4; ++nt)
          acc1[nt] = __builtin_amdgcn_mfma_f32_16x16x32_bf16(a, F1[ks*4+nt], acc1[nt], 0,0,0);
      }
#pragma unroll
      for (int ks=0; ks<8; ++ks){
        short8 a = *(const short8*)(ah1 + ks*512 + lane*8);
#pragma unroll
        for (int nt=0; nt<4; ++nt)
          acc1[nt] = __builtin_amdgcn_mfma_f32_16x16x32_bf16(a, F1[32+ks*4+nt], acc1[nt], 0,0,0);
      }
      float pr[4], h1v[4];
#pragma unroll
      for (int r=0; r<4; ++r){
        float iv = sigm (acc1[0][r] + bia1[0]);
        float fv = sigm (acc1[1][r] + bia1[1]);
        float gv = tanhx(acc1[2][r] + bia1[2]);
        float ov = sigm (acc1[3][r] + bia1[3]);
        float cc = fv*c1[r] + iv*gv;
        c1[r] = cc;
        float h = ov * tanhx(cc);
        h1v[r] = h;
        pr[r] = h * wo;
      }
      unsigned lo = cvtpk(h1v[0], h1v[1]);
      unsigned hi = cvtpk(h1v[2], h1v[3]);
      pv1 = ((u64)hi << 32) | lo;
      if (s < TT){
        pub_store(rbase + (colg*4+quad)*2 + 1, pv1 | tg64);
        // EARLY poll issue B: partner h1 words
        asm volatile(
          "global_load_dwordx2 %0, %3, off sc0 sc1\n\t"
          "global_load_dwordx2 %1, %4, off sc0 sc1\n\t"
          "global_load_dwordx2 %2, %5, off sc0 sc1"
          : "=&v"(e1a),"=&v"(e1b),"=&v"(e1c)
          : "v"(Pa+1),"v"(Pb+1),"v"(Pc+1) : "memory");
        // own h1 frags into next buffer
#pragma unroll
        for (int r=0; r<4; ++r)
          ah1_n[fragAddr(colg, quad*4 + r)] = (short)(pv1 >> (16*r));
      }
#pragma unroll
      for (int m=1; m<16; m<<=1){
#pragma unroll
        for (int r=0; r<4; ++r) pr[r] += __shfl_xor(pr[r], m, 64);
      }
      if (col16 == 0){
#pragma unroll
        for (int r=0; r<4; ++r) outacc[p][quad*4 + r][w] = pr[r];
      }
    } else if (s < TT){
      // s==0: tag-code-0 zero so stale data can't match T=1 at s==2.
      pub_store(rbase + (colg*4+quad)*2 + 1, 0ull);
    }

    if (s+1 < TT){
      int m = tid >> 4, d = tid & 15;
      ax_n[fragAddr(d, m)] = f2bf(xf);
    }

    // ---- check early polls; retry only while pending ----
    u64 w0a=0,w0b=0,w0c=0,w1a=0,w1b=0,w1c=0;
    if (s < TT){
      bool f0a=false,f0b=false,f0c=false;
      bool f1a=!doL1, f1b=!doL1, f1c=!doL1;
      // rule-#18: drain the early loads, then fence the scheduler so no
      // register use of e* is hoisted above the wait.
      asm volatile("s_waitcnt vmcnt(0)" ::: "memory");
      __builtin_amdgcn_sched_barrier(0);
      CHKW(e0a, w0a, f0a); CHKW(e0b, w0b, f0b); CHKW(e0c, w0c, f0c);
      if (doL1){ CHKW(e1a, w1a, f1a); CHKW(e1b, w1b, f1b); CHKW(e1c, w1c, f1c); }
      while (!(f0a & f0b & f0c & f1a & f1b & f1c)){
        u32x4 ta, tb, tc;
        asm volatile(
          "global_load_dwordx4 %0, %3, off sc0 sc1\n\t"
          "global_load_dwordx4 %1, %4, off sc0 sc1\n\t"
          "global_load_dwordx4 %2, %5, off sc0 sc1\n\t"
          "s_waitcnt vmcnt(0)"
          : "=&v"(ta),"=&v"(tb),"=&v"(tc)
          : "v"(Pa),"v"(Pb),"v"(Pc) : "memory");
        __builtin_amdgcn_sched_barrier(0);
        u64 h0w, h1w;
        h0w = (((u64)ta.y)<<32)|ta.x; h1w = (((u64)ta.w)<<32)|ta.z;
        CHKW(h0w, w0a, f0a); CHKW(h1w, w1a, f1a);
        h0w = (((u64)tb.y)<<32)|tb.x; h1w = (((u64)tb.w)<<32)|tb.z;
        CHKW(h0w, w0b, f0b); CHKW(h1w, w1b, f1b);
        h0w = (((u64)tc.y)<<32)|tc.x; h1w = (((u64)tc.w)<<32)|tc.z;
        CHKW(h0w, w0c, f0c); CHKW(h1w, w1c, f1c);
      }

      // partner frags into next buffer
      {
        short* sv = (short*)&w0a;
#pragma unroll
        for (int r=0; r<4; ++r) ah0_n[fragAddr(ka, qd*4 + r)] = sv[r];
        sv = (short*)&w0b;
#pragma unroll
        for (int r=0; r<4; ++r) ah0_n[fragAddr(kb, qd*4 + r)] = sv[r];
        sv = (short*)&w0c;
#pragma unroll
        for (int r=0; r<4; ++r) ah0_n[fragAddr(kc, qd*4 + r)] = sv[r];
      }
      if (doL1){
        short* sw = (short*)&w1a;
#pragma unroll
        for (int r=0; r<4; ++r) ah1_n[fragAddr(ka, qd*4 + r)] = sw[r];
        sw = (short*)&w1b;
#pragma unroll
        for (int r=0; r<4; ++r) ah1_n[fragAddr(kb, qd*4 + r)] = sw[r];
        sw = (short*)&w1c;
#pragma unroll
        for (int r=0; r<4; ++r) ah1_n[fragAddr(kc, qd*4 + r)] = sw[r];
      }
    }

    __syncthreads();

    // ---- out partials: t = s-1 (device-scope RMW, m20-verified) ----
    if (doL1 && tid < 16){
      float v = outacc[p][tid][0] + outacc[p][tid][1]
              + outacc[p][tid][2] + outacc[p][tid][3];
      if (c == 0) v += bos;
      atomicAdd(&out[(rowbase + tid)*TT + (s-1)], v);
    }
  }
#undef CHKW
}

// ---------------- launch ----------------
extern "C" void kernel_launch(void* const* d_in, const int* in_sizes, int n_in,
                              void* d_out, int out_size, void* d_ws, size_t ws_size,
                              hipStream_t stream)
{
  const float* x    = (const float*)d_in[0];
  const float* xs   = (const float*)d_in[1];
  const float* Wih0 = (const float*)d_in[2];
  const float* Whh0 = (const float*)d_in[3];
  const float* bih0 = (const float*)d_in[4];
  const float* bhh0 = (const float*)d_in[5];
  const float* Wih1 = (const float*)d_in[6];
  const float* Whh1 = (const float*)d_in[7];
  const float* bih1 = (const float*)d_in[8];
  const float* bhh1 = (const float*)d_in[9];
  const float* Ws   = (const float*)d_in[10];
  const float* bs   = (const float*)d_in[11];
  const float* Wo   = (const float*)d_in[12];
  const float* bo   = (const float*)d_in[13];
  float* out = (float*)d_out;

  char* ws = (char*)d_ws;
  short*    Wb0   = (short*)(ws);                // 589824
  short*    Wb1   = (short*)(ws + 589824);       // 1048576 -> 1638400
  float*    h0i   = (float*)(ws + 1638400);      // 524288  -> 2162688
  float*    b0cp  = (float*)(ws + 2162688);      // 4096    -> 2166784
  float*    b1cp  = (float*)(ws + 2166784);      // 4096    -> 2170880
  u64*      ring  = (u64*)(ws + 2170880);        // 1048576 -> 3219456 (~3.22 MB)

  int nswz = 16*36*512 + 16*64*512;
  hipLaunchKernelGGL(prep_weights, dim3((nswz+255)/256), dim3(256), 0, stream,
                     Wih0, Whh0, Wih1, Whh1, Wb0, Wb1);
  hipLaunchKernelGGL(prep_h0, dim3(512), dim3(256), 0, stream, xs, Ws, bs, h0i);
  hipLaunchKernelGGL(prep_bias, dim3(8), dim3(256), 0, stream, bih0, bhh0, bih1, bhh1, b0cp, b1cp);
  hipLaunchKernelGGL(prep_zero, dim3(1024), dim3(256), 0, stream, out, ring);

  hipLaunchKernelGGL(lstm_fused, dim3(128), dim3(256), 0, stream,
                     Wb0, Wb1, h0i, b0cp, b1cp, x, Wo, bo, ring, out);
}

// Round 6
// 1577.061 us; speedup vs baseline: 1.2176x; 1.2176x over previous
//
#include <hip/hip_runtime.h>

#define TT 365
#define BB 512
#define DD 16
#define HH 256
#define SS 32

typedef __attribute__((ext_vector_type(8))) short short8;
typedef __attribute__((ext_vector_type(4))) float f32x4;
typedef __attribute__((ext_vector_type(4))) unsigned u32x4;
typedef unsigned long long u64;

// Ring poison: tag bits (14,30) set in both dwords = tag-code 3; first poll of
// any address wants code 0 => mismatch; codes 1,2 are written before 3 recurs.
#define SENT 0x7FC07FC07FC07FC0ULL
// 2-bit generation tag per dword: bit14 (low bf16) + bit30 (high bf16).
// |h|<=1 => biased exp <= 127 => both bits are 0 in any published bf16.
#define TMASK64 0x4000400040004000ULL

__device__ __host__ inline short f2bf(float f){
  union { float f; unsigned u; } v; v.f = f;
  unsigned r = v.u + 0x7FFFu + ((v.u >> 16) & 1u);
  return (short)(r >> 16);
}
__device__ inline float sigm(float x){ return 1.0f/(1.0f+__expf(-x)); }
__device__ inline float tanhx(float x){ return 2.0f/(1.0f+__expf(-2.0f*x)) - 1.0f; }

// RNE f32x2 -> packed bf16x2 (same rounding as f2bf; h is never NaN)
__device__ inline unsigned cvtpk(float a, float b){
  unsigned r;
  asm("v_cvt_pk_bf16_f32 %0, %1, %2" : "=v"(r) : "v"(a), "v"(b));
  return r;
}

// A-fragment address (shorts) in an 8KB K=256 region for mfma_16x16x32 A-layout.
__device__ inline int fragAddr(int k, int m){
  return ((k>>5)*512) + ((((k&31)>>3)*16 + m)*8) + (k&7);
}

// Coherence-point store (HW-verified visible to sc0+sc1 polls in R2/R3/R5).
__device__ inline void pub_store(u64* p, u64 v){
  asm volatile("global_store_dwordx2 %0, %1, off sc0 sc1"
               :: "v"(p), "v"(v) : "memory");
}

// Raw barrier: LDS-drain only. Publish stores / polls / atomics stay in flight
// (__syncthreads would emit s_waitcnt vmcnt(0) and serialize coherence RTTs).
#define RAW_BAR() do{ \
    asm volatile("s_waitcnt lgkmcnt(0)\n\ts_barrier" ::: "memory"); \
    __builtin_amdgcn_sched_barrier(0); }while(0)

// ---------------- prep kernels ----------------
__global__ void prep_weights(const float* __restrict__ Wih0, const float* __restrict__ Whh0,
                             const float* __restrict__ Wih1, const float* __restrict__ Whh1,
                             short* __restrict__ Wb0, short* __restrict__ Wb1)
{
  int idx = blockIdx.x*blockDim.x + threadIdx.x;
  const int n0 = 16*36*512;
  const int n1 = 16*64*512;
  if (idx < n0){
    int frag = idx >> 9, pos = idx & 511;
    int lane = pos >> 3, jj = pos & 7;
    int slot = frag / 36, rem = frag % 36;
    int ks = rem >> 2, nt = rem & 3;
    int n = nt*256 + slot*16 + (lane & 15);
    float v = 0.0f;
    if (ks == 0){
      int k32 = (lane>>4)*8 + jj;
      if (k32 < 16) v = Wih0[n*16 + k32];
    } else {
      int k = (ks-1)*32 + (lane>>4)*8 + jj;
      v = Whh0[n*256 + k];
    }
    Wb0[idx] = f2bf(v);
  } else if (idx < n0 + n1){
    int e = idx - n0;
    int frag = e >> 9, pos = e & 511;
    int lane = pos >> 3, jj = pos & 7;
    int slot = frag >> 6, rem = frag & 63;
    int ks = rem >> 2, nt = rem & 3;
    int n = nt*256 + slot*16 + (lane & 15);
    int k = ks*32 + (lane>>4)*8 + jj;
    float v = (k < 256) ? Wih1[n*256 + k] : Whh1[n*256 + (k-256)];
    Wb1[e] = f2bf(v);
  }
}

__global__ void prep_h0(const float* __restrict__ xs, const float* __restrict__ Ws,
                        const float* __restrict__ bs, float* __restrict__ h0init)
{
  int i = blockIdx.x*blockDim.x + threadIdx.x;
  int b = i >> 8, jj = i & 255;
  float s = bs[jj];
  const float* xr = xs + b*SS;
  const float* wr = Ws + jj*SS;
#pragma unroll
  for (int q=0;q<SS;++q) s += xr[q]*wr[q];
  h0init[i] = s;
}

__global__ void prep_bias(const float* __restrict__ a0, const float* __restrict__ a1,
                          const float* __restrict__ a2, const float* __restrict__ a3,
                          float* __restrict__ b0o, float* __restrict__ b1o)
{
  int i = threadIdx.x + blockIdx.x*blockDim.x;
  if (i < 1024) b0o[i] = a0[i] + a1[i];
  else if (i < 2048) b1o[i-1024] = a2[i-1024] + a3[i-1024];
}

// zero out (atomicAdd target) + pre-poison ring (tag code 3 => no false match)
__global__ void prep_zero(float* __restrict__ out, u64* __restrict__ ring)
{
  int i = blockIdx.x*blockDim.x + threadIdx.x;
  if (i < BB*TT) out[i] = 0.0f;
  if (i < 131072) ring[i] = SENT;   // 2 slots x 32 g x 2048 u64 = 1MB
}

// ---------------- persistent fused LSTM ----------------
// 128 blocks x 256 threads; g = bid&31 (16 batch rows), c = bid>>5 (64 hidden cols).
// Weights register/AGPR-resident. Lag pipeline: superstep s runs L0@t=s, L1@t=s-1.
//
// Exchange: generation-tagged packets {h0(s), h1(s-1)}, slot s&1, 2-BIT tag
// T=(s>>1)&3 in (bit14,bit30) of every dword (Delta-s=8 to collide; skew<=1 via
// mutual consumption => no ABA). Read-only sc0+sc1 polls; no atomics in exchange.
//
// Schedule per superstep s (2 RAW barriers, never a vmcnt drain on fast path):
//  B0 | flush out(t=s-2) | issue h1(s-2) polls  <- published a FULL step ago: round-0 hit;
//  L0: 36 MFMA -> epi -> publish h0(s) -> own h0 frags        RTT hides under L0
//  L1a: 32 MFMA (Wih1 x AH0[p])
//  check h1 polls (vmcnt(1): only h0 store is newer) -> fill AH1 (own pv1_prev + partner)
//  issue h0(s) polls  <- ~900cy after my publish: beats partner-store landing (R5 lesson)
//  B1 | L1b: 32 MFMA (Whh1 x AH1) -> epi -> publish h1(s-1) -> reduce -> outacc[p]
//  tail: check h0 polls (vmcnt(1): only h1 store newer) -> partner h0 frags -> AX stage
// Counted vmcnt is safe: in-order retirement; N = #vmem ops issued after the
// waited-for ops (older stragglers only strengthen the wait).
__global__ __launch_bounds__(256, 1) void lstm_fused(
    const short* __restrict__ Wb0, const short* __restrict__ Wb1,
    const float* __restrict__ h0i, const float* __restrict__ b0c,
    const float* __restrict__ b1c, const float* __restrict__ x,
    const float* __restrict__ Wo, const float* __restrict__ bo,
    u64* __restrict__ ring, float* __restrict__ out)
{
  __shared__ alignas(16) short AX[2][512];
  __shared__ alignas(16) short AH0[2][4096];
  __shared__ alignas(16) short AH1[4096];       // single buffer; filled mid-step, used post-B1
  __shared__ float outacc[2][16][4];

  const int tid  = threadIdx.x;
  const int w    = tid >> 6;
  const int lane = tid & 63;
  const int col16= lane & 15;
  const int quad = lane >> 4;
  const int c    = blockIdx.x >> 5;
  const int g    = blockIdx.x & 31;
  const int rowbase = g * 16;
  const int slot = c*4 + w;
  const int colg = slot*16 + col16;

  // ---- register-resident weight fragments ----
  short8 F0[36], F1[64];
  {
    const short8* p0 = (const short8*)Wb0 + slot*36*64 + lane;
#pragma unroll
    for (int f=0; f<36; ++f) F0[f] = p0[f*64];
    const short8* p1 = (const short8*)Wb1 + slot*64*64 + lane;
#pragma unroll
    for (int f=0; f<64; ++f) F1[f] = p1[f*64];
  }
  float bia0[4], bia1[4];
#pragma unroll
  for (int nt=0; nt<4; ++nt){
    bia0[nt] = b0c[nt*256 + slot*16 + col16];
    bia1[nt] = b1c[nt*256 + slot*16 + col16];
  }
  const float wo = Wo[colg];
  const float bos = bo[0];

  // ---- init ----
  float c0[4], c1[4];
#pragma unroll
  for (int r=0; r<4; ++r){
    c0[r] = h0i[(rowbase + quad*4 + r)*HH + colg];
    c1[r] = c0[r];
  }
  for (int i = tid; i < 4096; i += 256){
    int m = i >> 8, k = i & 255;
    short v = f2bf(h0i[(rowbase+m)*HH + k]);
    int a = fragAddr(k,m);
    AH0[0][a] = v;        // h0(-1) = h0init
    AH1[a]    = v;        // h1(-1) = h0init (used at s==1)
  }
  {
    int m = tid >> 4, d = tid & 15;
    AX[0][fragAddr(d, m)] = f2bf(x[(rowbase+m)*TT*DD + d]);
    AX[0][fragAddr(16 + d, m)] = 0;
    AX[1][fragAddr(16 + d, m)] = 0;
  }
  __syncthreads();

  const f32x4 zero = {0.0f,0.0f,0.0f,0.0f};
  const int qd = tid & 3;
  const int cl = (tid >> 2) & 63;
  const int ka = (((c + 1) & 3) << 6) + cl;
  const int kb = (((c + 2) & 3) << 6) + cl;
  const int kc = (((c + 3) & 3) << 6) + cl;

  u64 pv1_prev = 0;   // my h1(s-2) packed, carried across the step boundary

#define CHKW(tv,dst,fl,TG) do{ u64 _t=(tv); \
    if(!(fl) && ((_t & TMASK64)==(TG))){ (dst)=_t & ~TMASK64; (fl)=true; } }while(0)

  for (int s=0; s<=TT; ++s){
    const bool doL0 = (s < TT);
    const bool doL1 = (s >= 1);
    const bool doH1x = (s >= 2);          // h1 exchange + AH1 rewrite active
    const int  p = s & 1;
    const unsigned T0 = (s>>1)&3;
    const unsigned w32_0 = ((T0&1)?0x4000u:0u) | ((T0&2)?0x40000000u:0u);
    const u64 tg0 = ((u64)w32_0<<32)|w32_0;
    const int  q1 = (s-1)&1;
    const unsigned T1 = ((s-1)>>1)&3;
    const unsigned w32_1 = ((T1&1)?0x4000u:0u) | ((T1&2)?0x40000000u:0u);
    const u64 tg1 = ((u64)w32_1<<32)|w32_1;

    short* ax   = AX[p];   short* ah0   = AH0[p];
    short* ax_n = AX[p^1]; short* ah0_n = AH0[p^1];
    u64* rb0 = ring + (p*32+g)*2048;
    u64* rb1 = ring + (q1*32+g)*2048;
    u64* P0a = rb0 + (ka*4+qd)*2;
    u64* P0b = rb0 + (kb*4+qd)*2;
    u64* P0c = rb0 + (kc*4+qd)*2;
    u64* P1a = rb1 + (ka*4+qd)*2 + 1;
    u64* P1b = rb1 + (kb*4+qd)*2 + 1;
    u64* P1c = rb1 + (kc*4+qd)*2 + 1;

    RAW_BAR();  // B0: prev-step LDS writes visible (vmcnt untouched)

    // flush out partials for t=s-2 (outacc[p^1] written at step s-1; fire-and-forget)
    if (doH1x && tid < 16){
      float v = outacc[p^1][tid][0] + outacc[p^1][tid][1]
              + outacc[p^1][tid][2] + outacc[p^1][tid][3];
      if (c == 0) v += bos;
      atomicAdd(&out[(rowbase + tid)*TT + (s-2)], v);
    }

    // x prefetch (cached load; issued before poll asm => older in vmcnt order)
    float xf = 0.0f;
    if (s+1 < TT){
      int m = tid >> 4, d = tid & 15;
      xf = x[(rowbase+m)*TT*DD + (s+1)*DD + d];
    }

    // ---- issue h1(s-2) polls: target published a full step ago -> round-0 hit ----
    u64 e1a=0, e1b=0, e1c=0;
    if (doH1x){
      asm volatile(
        "global_load_dwordx2 %0, %3, off sc0 sc1\n\t"
        "global_load_dwordx2 %1, %4, off sc0 sc1\n\t"
        "global_load_dwordx2 %2, %5, off sc0 sc1"
        : "=&v"(e1a),"=&v"(e1b),"=&v"(e1c)
        : "v"(P1a),"v"(P1b),"v"(P1c) : "memory");
    }

    // ---- L0: 36 MFMA -> epi -> publish h0(s) -> own h0 frags ----
    u64 pv0 = 0;
    if (doL0){
      f32x4 acc0[4];
#pragma unroll
      for (int nt=0; nt<4; ++nt) acc0[nt] = zero;
      {
        short8 a = *(const short8*)(ax + lane*8);
#pragma unroll
        for (int nt=0; nt<4; ++nt)
          acc0[nt] = __builtin_amdgcn_mfma_f32_16x16x32_bf16(a, F0[nt], acc0[nt], 0,0,0);
      }
#pragma unroll
      for (int ks=0; ks<8; ++ks){
        short8 a = *(const short8*)(ah0 + ks*512 + lane*8);
#pragma unroll
        for (int nt=0; nt<4; ++nt)
          acc0[nt] = __builtin_amdgcn_mfma_f32_16x16x32_bf16(a, F0[(ks+1)*4+nt], acc0[nt], 0,0,0);
      }
      float h0v[4];
#pragma unroll
      for (int r=0; r<4; ++r){
        float iv = sigm (acc0[0][r] + bia0[0]);
        float fv = sigm (acc0[1][r] + bia0[1]);
        float gv = tanhx(acc0[2][r] + bia0[2]);
        float ov = sigm (acc0[3][r] + bia0[3]);
        float cc = fv*c0[r] + iv*gv;
        c0[r] = cc;
        h0v[r] = ov * tanhx(cc);
      }
      pv0 = (((u64)cvtpk(h0v[2], h0v[3])) << 32) | cvtpk(h0v[0], h0v[1]);
      pub_store(rb0 + (colg*4+quad)*2, pv0 | tg0);
#pragma unroll
      for (int r=0; r<4; ++r)
        ah0_n[fragAddr(colg, quad*4 + r)] = (short)(pv0 >> (16*r));
    }

    // ---- L1a: Wih1 x h0(s-1) part (AH0[p]) ----
    f32x4 acc1[4];
#pragma unroll
    for (int nt=0; nt<4; ++nt) acc1[nt] = zero;
    if (doL1){
#pragma unroll
      for (int ks=0; ks<8; ++ks){
        short8 a = *(const short8*)(ah0 + ks*512 + lane*8);
#pragma unroll
        for (int nt=0; nt<4; ++nt)
          acc1[nt] = __builtin_amdgcn_mfma_f32_16x16x32_bf16(a, F1[ks*4+nt], acc1[nt], 0,0,0);
      }
    }

    // ---- check h1 polls; fill AH1 (own pv1_prev + partners) ----
    if (doH1x){
      __builtin_amdgcn_sched_barrier(0);   // keep L1a above the wait
      if (doL0) asm volatile("s_waitcnt vmcnt(1)" ::: "memory");  // newer: h0 store
      else      asm volatile("s_waitcnt vmcnt(0)" ::: "memory");
      __builtin_amdgcn_sched_barrier(0);   // rule-#18 fence
      u64 w1a=0,w1b=0,w1c=0;
      bool f1a=false,f1b=false,f1c=false;
      CHKW(e1a, w1a, f1a, tg1); CHKW(e1b, w1b, f1b, tg1); CHKW(e1c, w1c, f1c, tg1);
      while (!(f1a & f1b & f1c)){
        u64 t0,t1,t2;
        asm volatile(
          "global_load_dwordx2 %0, %3, off sc0 sc1\n\t"
          "global_load_dwordx2 %1, %4, off sc0 sc1\n\t"
          "global_load_dwordx2 %2, %5, off sc0 sc1\n\t"
          "s_waitcnt vmcnt(0)"
          : "=&v"(t0),"=&v"(t1),"=&v"(t2)
          : "v"(P1a),"v"(P1b),"v"(P1c) : "memory");
        __builtin_amdgcn_sched_barrier(0);
        CHKW(t0, w1a, f1a, tg1); CHKW(t1, w1b, f1b, tg1); CHKW(t2, w1c, f1c, tg1);
      }
      // own h1(s-2) from register; partners from polls
#pragma unroll
      for (int r=0; r<4; ++r)
        AH1[fragAddr(colg, quad*4 + r)] = (short)(pv1_prev >> (16*r));
      {
        short* sv = (short*)&w1a;
#pragma unroll
        for (int r=0; r<4; ++r) AH1[fragAddr(ka, qd*4 + r)] = sv[r];
        sv = (short*)&w1b;
#pragma unroll
        for (int r=0; r<4; ++r) AH1[fragAddr(kb, qd*4 + r)] = sv[r];
        sv = (short*)&w1c;
#pragma unroll
        for (int r=0; r<4; ++r) AH1[fragAddr(kc, qd*4 + r)] = sv[r];
      }
    }

    // ---- issue h0(s) polls (~900cy after my publish; return hides under L1b) ----
    u64 e0a=0, e0b=0, e0c=0;
    if (doL0){
      asm volatile(
        "global_load_dwordx2 %0, %3, off sc0 sc1\n\t"
        "global_load_dwordx2 %1, %4, off sc0 sc1\n\t"
        "global_load_dwordx2 %2, %5, off sc0 sc1"
        : "=&v"(e0a),"=&v"(e0b),"=&v"(e0c)
        : "v"(P0a),"v"(P0b),"v"(P0c) : "memory");
    }

    RAW_BAR();  // B1: AH1 ready (h0 polls stay in flight!)

    // ---- L1b: Whh1 x h1(s-2) part (AH1) -> epi -> publish h1(s-1) -> reduce ----
    u64 pv1 = 0;
    if (doL1){
#pragma unroll
      for (int ks=0; ks<8; ++ks){
        short8 a = *(const short8*)(AH1 + ks*512 + lane*8);
#pragma unroll
        for (int nt=0; nt<4; ++nt)
          acc1[nt] = __builtin_amdgcn_mfma_f32_16x16x32_bf16(a, F1[32+ks*4+nt], acc1[nt], 0,0,0);
      }
      float pr[4], h1v[4];
#pragma unroll
      for (int r=0; r<4; ++r){
        float iv = sigm (acc1[0][r] + bia1[0]);
        float fv = sigm (acc1[1][r] + bia1[1]);
        float gv = tanhx(acc1[2][r] + bia1[2]);
        float ov = sigm (acc1[3][r] + bia1[3]);
        float cc = fv*c1[r] + iv*gv;
        c1[r] = cc;
        float h = ov * tanhx(cc);
        h1v[r] = h;
        pr[r] = h * wo;
      }
      pv1 = (((u64)cvtpk(h1v[2], h1v[3])) << 32) | cvtpk(h1v[0], h1v[1]);
      if (doL0)
        pub_store(rb0 + (colg*4+quad)*2 + 1, pv1 | tg0);
#pragma unroll
      for (int m=1; m<16; m<<=1){
#pragma unroll
        for (int r=0; r<4; ++r) pr[r] += __shfl_xor(pr[r], m, 64);
      }
      if (col16 == 0){
#pragma unroll
        for (int r=0; r<4; ++r) outacc[p][quad*4 + r][w] = pr[r];
      }
    }

    // ---- tail: check h0 polls -> partner h0 frags -> AX stage ----
    if (doL0){
      __builtin_amdgcn_sched_barrier(0);
      if (doL1) asm volatile("s_waitcnt vmcnt(1)" ::: "memory");  // newer: h1 store
      else      asm volatile("s_waitcnt vmcnt(0)" ::: "memory");
      __builtin_amdgcn_sched_barrier(0);
      u64 w0a=0,w0b=0,w0c=0;
      bool f0a=false,f0b=false,f0c=false;
      CHKW(e0a, w0a, f0a, tg0); CHKW(e0b, w0b, f0b, tg0); CHKW(e0c, w0c, f0c, tg0);
      while (!(f0a & f0b & f0c)){
        u64 t0,t1,t2;
        asm volatile(
          "global_load_dwordx2 %0, %3, off sc0 sc1\n\t"
          "global_load_dwordx2 %1, %4, off sc0 sc1\n\t"
          "global_load_dwordx2 %2, %5, off sc0 sc1\n\t"
          "s_waitcnt vmcnt(0)"
          : "=&v"(t0),"=&v"(t1),"=&v"(t2)
          : "v"(P0a),"v"(P0b),"v"(P0c) : "memory");
        __builtin_amdgcn_sched_barrier(0);
        CHKW(t0, w0a, f0a, tg0); CHKW(t1, w0b, f0b, tg0); CHKW(t2, w0c, f0c, tg0);
      }
      {
        short* sv = (short*)&w0a;
#pragma unroll
        for (int r=0; r<4; ++r) ah0_n[fragAddr(ka, qd*4 + r)] = sv[r];
        sv = (short*)&w0b;
#pragma unroll
        for (int r=0; r<4; ++r) ah0_n[fragAddr(kb, qd*4 + r)] = sv[r];
        sv = (short*)&w0c;
#pragma unroll
        for (int r=0; r<4; ++r) ah0_n[fragAddr(kc, qd*4 + r)] = sv[r];
      }
      if (s+1 < TT){
        int m = tid >> 4, d = tid & 15;
        ax_n[fragAddr(d, m)] = f2bf(xf);
      }
    }

    pv1_prev = pv1;
  }
#undef CHKW

  // ---- final flush: t = TT-1 lives in outacc[TT&1] ----
  RAW_BAR();
  if (tid < 16){
    const int pf = TT & 1;
    float v = outacc[pf][tid][0] + outacc[pf][tid][1]
            + outacc[pf][tid][2] + outacc[pf][tid][3];
    if (c == 0) v += bos;
    atomicAdd(&out[(rowbase + tid)*TT + (TT-1)], v);
  }
}

// ---------------- launch ----------------
extern "C" void kernel_launch(void* const* d_in, const int* in_sizes, int n_in,
                              void* d_out, int out_size, void* d_ws, size_t ws_size,
                              hipStream_t stream)
{
  const float* x    = (const float*)d_in[0];
  const float* xs   = (const float*)d_in[1];
  const float* Wih0 = (const float*)d_in[2];
  const float* Whh0 = (const float*)d_in[3];
  const float* bih0 = (const float*)d_in[4];
  const float* bhh0 = (const float*)d_in[5];
  const float* Wih1 = (const float*)d_in[6];
  const float* Whh1 = (const float*)d_in[7];
  const float* bih1 = (const float*)d_in[8];
  const float* bhh1 = (const float*)d_in[9];
  const float* Ws   = (const float*)d_in[10];
  const float* bs   = (const float*)d_in[11];
  const float* Wo   = (const float*)d_in[12];
  const float* bo   = (const float*)d_in[13];
  float* out = (float*)d_out;

  char* ws = (char*)d_ws;
  short*    Wb0   = (short*)(ws);                // 589824
  short*    Wb1   = (short*)(ws + 589824);       // 1048576 -> 1638400
  float*    h0i   = (float*)(ws + 1638400);      // 524288  -> 2162688
  float*    b0cp  = (float*)(ws + 2162688);      // 4096    -> 2166784
  float*    b1cp  = (float*)(ws + 2166784);      // 4096    -> 2170880
  u64*      ring  = (u64*)(ws + 2170880);        // 1048576 -> 3219456 (~3.22 MB)

  int nswz = 16*36*512 + 16*64*512;
  hipLaunchKernelGGL(prep_weights, dim3((nswz+255)/256), dim3(256), 0, stream,
                     Wih0, Whh0, Wih1, Whh1, Wb0, Wb1);
  hipLaunchKernelGGL(prep_h0, dim3(512), dim3(256), 0, stream, xs, Ws, bs, h0i);
  hipLaunchKernelGGL(prep_bias, dim3(8), dim3(256), 0, stream, bih0, bhh0, bih1, bhh1, b0cp, b1cp);
  hipLaunchKernelGGL(prep_zero, dim3(1024), dim3(256), 0, stream, out, ring);

  hipLaunchKernelGGL(lstm_fused, dim3(128), dim3(256), 0, stream,
                     Wb0, Wb1, h0i, b0cp, b1cp, x, Wo, bo, ring, out);
}